// Round 11
// baseline (150.091 us; speedup 1.0000x reference)
//
#include <hip/hip_runtime.h>

#define MA 64
#define F 128
#define NF 16
#define HID 512
#define SLAB 8192   // one B-slab: 64 rows x 128 fp8, UNPADDED (XOR-swizzled)
#define LDWB 144    // wL row stride bytes (64 bf16 + 8 pad elems)
#define LDT1B 1040  // t1 row stride bytes (512 bf16 + 8 pad elems)
// LDS map: slabs 0..16 at f*8192 (slab0 = h, slab f+1 = u_f) = 139,264 B;
// wL double-buffer above; t1 overlays slabs 0..8 during GEMM2.
#define WL0 139264
#define WL1 148480
// 16B-granular XOR swizzle for the unpadded slabs: spreads the 16 rows of a
// column-slice across 8 distinct 16B slots -> bank-even (8 dwords/bank) for
// the phase-2 b128 reads. Applied on BOTH write (4B grains) and read (16B).
#define SWZ(row, col) ((((row) * 128) + (col)) ^ (((row) & 7) << 4))

typedef float  float4v __attribute__((ext_vector_type(4)));
typedef short  short8  __attribute__((ext_vector_type(8)));
typedef int    int8v   __attribute__((ext_vector_type(8)));

// pack two fp32 -> (bf16(y)<<16)|bf16(x), round-half-up via +0x8000 then v_perm
static __device__ __forceinline__ unsigned int pack2bf(float x, float y) {
    unsigned int a = __float_as_uint(x) + 0x8000u;
    unsigned int b = __float_as_uint(y) + 0x8000u;
    return __builtin_amdgcn_perm(b, a, 0x07060302u);
}
static __device__ __forceinline__ unsigned short f2bf1(float x) {
    return (unsigned short)((__float_as_uint(x) + 0x8000u) >> 16);
}
// pack 4 fp32 -> 4 fp8 e4m3 (RNE, saturating) in one dword
static __device__ __forceinline__ unsigned int pk4fp8(float a, float b, float c, float d) {
    int p = __builtin_amdgcn_cvt_pk_fp8_f32(a, b, 0, false);
    p = __builtin_amdgcn_cvt_pk_fp8_f32(c, d, p, true);
    return (unsigned int)p;
}

// lgkm-only barrier: LDS producer/consumer sync WITHOUT draining vmcnt.
#define LGKM_BAR() do {                                        \
    asm volatile("s_waitcnt lgkmcnt(0)" ::: "memory");         \
    __builtin_amdgcn_s_barrier();                              \
    asm volatile("" ::: "memory");                             \
} while (0)

// ---- Pack W1 as fp8 MX A-frags (16x16x128) of W1^T; W2 as bf16 A-frags
// (16x16x32) of W2^T. Direct gather. (unchanged)
__global__ void pack_frags(const float* __restrict__ W1, const float* __restrict__ W2,
                           unsigned char* __restrict__ w1p, unsigned short* __restrict__ w2p) {
    int gid  = blockIdx.x * 4 + (threadIdx.x >> 6);
    int lane = threadIdx.x & 63;
    int arow = lane & 15;
    int kq   = lane >> 4;
    if (gid < 544) {                           // W1: kt (17 over K=2176, 128 each) x jt (32)
        int kt = gid >> 5, jt = gid & 31;
        const float* base = W1 + (size_t)(kt * 128 + kq * 32) * HID + jt * 16 + arow;
        unsigned int o[8];
        #pragma unroll
        for (int p = 0; p < 8; p++)
            o[p] = pk4fp8(base[(p * 4 + 0) * HID], base[(p * 4 + 1) * HID],
                          base[(p * 4 + 2) * HID], base[(p * 4 + 3) * HID]);
        unsigned char* dst = w1p + ((size_t)gid * 64 + lane) * 32;
        *(uint4*)dst        = (uint4){o[0], o[1], o[2], o[3]};
        *(uint4*)(dst + 16) = (uint4){o[4], o[5], o[6], o[7]};
    } else if (gid < 544 + 128) {              // W2: kt (16 over J=512) x mt (8 over 128)
        int g2 = gid - 544;
        int kt = g2 >> 3, mt = g2 & 7;
        const float* base = W2 + (size_t)(kt * 32 + kq * 8) * F + mt * 16 + arow;
        short8 o;
        #pragma unroll
        for (int j = 0; j < 8; j++) o[j] = (short)f2bf1(base[j * F]);
        *(short8*)(w2p + ((size_t)g2 * 64 + lane) * 8) = o;
    }
}

// ---- Main fused kernel: ONE molecule per block, 1024 threads = 16 waves ----
// DECOUPLED TWO-PHASE STRUCTURE. r10 proved the binder is the serialized
// per-filter dependency chain (barrier count 19->12 was a clean null), and
// u_f = w_f @ h has NO dependence on previous filters -- the seriality was
// an artifact of the 2-tile double buffer. All 17 B-slabs (h + 16 u) at fp8
// unpadded = 139.3KB fit in the 160KB LDS:
//  PHASE 1 (17 short lgkm intervals): w_f -> wL dbuf -> u_f -> slab f+1.
//   4 bf16 MFMA + 4 exps per wave per interval; no GEMM1 inside.
//  PHASE 2 (ZERO barriers): GEMM1 streams all 17 K-segments; W1 A-frags
//   prefetched from L2 (read exactly once -- r4/r7 constraint), B-frags from
//   resident slabs. Waves drift freely; LDS/MFMA/VMEM overlap program-wide.
// Slabs are XOR-swizzled (SWZ) since unpadded 128B rows would be 32-way
// column-bank-conflicted; swizzle applied on both write and read sides.
__launch_bounds__(1024, 4)
__global__ void node_conv_mfma(const int* __restrict__ z, const float* __restrict__ rr,
        const float* __restrict__ h, const float* __restrict__ dist,
        const float* __restrict__ wid, const float* __restrict__ b1,
        const float* __restrict__ b2,
        const unsigned char* __restrict__ w1p, const unsigned short* __restrict__ w2p,
        float* __restrict__ out) {
    const int n = blockIdx.x;                  // molecule index
    const int tid = threadIdx.x;
    const int lane = tid & 63;
    const int wave = tid >> 6;                 // 0..15
    const int arow = lane & 15;
    const int quad = lane >> 4;
    const int kgrp = quad * 8;
    const int whi = wave >> 1;                 // u-GEMM/GEMM2: c-slice
    const int wlo = wave & 1;                  // u-GEMM/GEMM2: a-pair selector

    __shared__ __attribute__((aligned(16))) unsigned char lds[157696];
    __shared__ float r_lds[MA][5];             // xyz + mask, stride-5

    const int N = gridDim.x;
    const float* hg = h + (size_t)n * MA * F;

    // ---- z / r passthrough + r/mask staging ----
    if (tid < MA) {
        int zi = z[n * MA + tid];
        out[(size_t)n * MA + tid] = (float)zi;
        r_lds[tid][0] = rr[(n * MA + tid) * 3 + 0];
        r_lds[tid][1] = rr[(n * MA + tid) * 3 + 1];
        r_lds[tid][2] = rr[(n * MA + tid) * 3 + 2];
        r_lds[tid][3] = (zi > -1) ? 1.0f : 0.0f;
    }
    if (tid < MA * 3)
        out[(size_t)N * MA + (size_t)n * MA * 3 + tid] = rr[(size_t)n * MA * 3 + tid];

    // ---- stage h -> slab 0 (row-major fp8, swizzled) ----
    for (int i = tid; i < MA * F / 4; i += 1024) {
        float4 v = ((const float4*)hg)[i];
        int a = i >> 5, c4 = (i & 31) * 4;
        *(unsigned int*)&lds[SWZ(a, c4)] = pk4fp8(v.x, v.y, v.z, v.w);
    }
    // ---- hT A-fragments in registers (bf16): lane holds h[b][c], c = whi*16+arow ----
    short8 ah[2];
    {
        int c = whi * 16 + arow;
        #pragma unroll
        for (int ks2 = 0; ks2 < 2; ks2++)
            #pragma unroll
            for (int j = 0; j < 8; j++)
                ah[ks2][j] = (short)f2bf1(hg[(size_t)(ks2 * 32 + kgrp + j) * F + c]);
    }
    // ---- seg-0 W1 A-frag pair: issue now; completes during phase 1 ----
    int8v p0, p1, q0, q1;
    {
        const unsigned char* pp = w1p + ((size_t)((wave * 2) * 64 + lane)) * 32;
        p0 = *(const int8v*)pp;
        p1 = *(const int8v*)(pp + 2048);
    }
    __syncthreads();                           // r_lds + slab0 visible (full drain, once)

    // ---- per-thread pairwise distances (4 pairs/thread), mask folded in ----
    const int wa = tid >> 4;                   // 0..63
    const int wb0 = (tid & 15) * 4;            // 0,4,..,60
    float dpre[4];
    {
        float ax = r_lds[wa][0], ay = r_lds[wa][1], az = r_lds[wa][2];
        float am = r_lds[wa][3];
        #pragma unroll
        for (int j = 0; j < 4; j++) {
            float dx = ax - r_lds[wb0 + j][0];
            float dy = ay - r_lds[wb0 + j][1];
            float dz = az - r_lds[wb0 + j][2];
            float d = sqrtf(dx * dx + dy * dy + dz * dz + 1e-12f);
            float mm = am * r_lds[wb0 + j][3];
            dpre[j] = d + (1.0f - mm) * 1e4f;
        }
    }

    // ---- phase helpers ----
    auto EXPW = [&](int fidx, int wlOff) {     // exp filter fidx -> wL slot
        float mu = dist[fidx];
        float isg = 1.0f / wid[fidx];
        float e[4];
        #pragma unroll
        for (int j = 0; j < 4; j++) {
            float t = dpre[j] - mu;
            e[j] = 5.0f * __expf(-t * t * isg);
        }
        uint2 wp = { pack2bf(e[0], e[1]), pack2bf(e[2], e[3]) };
        *(uint2*)&lds[wlOff + wa * LDWB + wb0 * 2] = wp;
    };
    const float4v zf = {0.f, 0.f, 0.f, 0.f};
    auto UG = [&](int wlOff, int slabOff) {    // u = h^T w (bf16); fp8 store (swizzled)
        float4v ud0 = zf, ud1 = zf;
        #pragma unroll
        for (int ks2 = 0; ks2 < 2; ks2++) {
            short8 bw0 = *(const short8*)&lds[wlOff + ((wlo * 2 + 0) * 16 + arow) * LDWB + (ks2 * 32 + kgrp) * 2];
            ud0 = __builtin_amdgcn_mfma_f32_16x16x32_bf16(ah[ks2], bw0, ud0, 0, 0, 0);
            short8 bw1 = *(const short8*)&lds[wlOff + ((wlo * 2 + 1) * 16 + arow) * LDWB + (ks2 * 32 + kgrp) * 2];
            ud1 = __builtin_amdgcn_mfma_f32_16x16x32_bf16(ah[ks2], bw1, ud1, 0, 0, 0);
        }
        unsigned int u0 = pk4fp8(ud0[0], ud0[1], ud0[2], ud0[3]);
        unsigned int u1 = pk4fp8(ud1[0], ud1[1], ud1[2], ud1[3]);
        *(unsigned int*)&lds[slabOff + SWZ((wlo * 2 + 0) * 16 + arow, whi * 16 + quad * 4)] = u0;
        *(unsigned int*)&lds[slabOff + SWZ((wlo * 2 + 1) * 16 + arow, whi * 16 + quad * 4)] = u1;
    };

    // ================= PHASE 1: produce all u_f slabs =================
    EXPW(0, WL0);
    LGKM_BAR();                                // w0 visible
    for (int f = 0; f < NF; f++) {
        const int wlR = (f & 1) ? WL1 : WL0;
        const int wlW = (f & 1) ? WL0 : WL1;
        UG(wlR, (f + 1) * SLAB);               // u_f -> slab f+1 (no reader yet)
        if (f < NF - 1) EXPW(f + 1, wlW);      // w_{f+1} -> other wL buffer
        LGKM_BAR();                            // u_f + w_{f+1} visible (17 short bars)
    }

    // ================= PHASE 2: GEMM1, ZERO barriers =================
    float4v acc[2][4];                         // [mt = j-tile][at = a-tile] = 32 AGPRs
    #pragma unroll
    for (int i = 0; i < 2; i++)
        #pragma unroll
        for (int jv = 0; jv < 4; jv++) acc[i][jv] = zf;

    for (int f = 0; f <= NF; f++) {
        if (f < NF) {                          // prefetch next segment's A-frag pair
            const unsigned char* pq = w1p + ((size_t)(((f + 1) * 32 + wave * 2) * 64 + lane)) * 32;
            q0 = *(const int8v*)pq;
            q1 = *(const int8v*)(pq + 2048);
        }
        const int sb = f * SLAB;
        #pragma unroll
        for (int at = 0; at < 4; at++) {
            const int rowb = at * 16 + arow;
            uint4 lo = *(const uint4*)&lds[sb + SWZ(rowb, quad * 32)];
            uint4 hi = *(const uint4*)&lds[sb + SWZ(rowb, quad * 32 + 16)];
            int8v bfr;
            bfr[0] = (int)lo.x; bfr[1] = (int)lo.y; bfr[2] = (int)lo.z; bfr[3] = (int)lo.w;
            bfr[4] = (int)hi.x; bfr[5] = (int)hi.y; bfr[6] = (int)hi.z; bfr[7] = (int)hi.w;
            acc[0][at] = __builtin_amdgcn_mfma_scale_f32_16x16x128_f8f6f4(
                p0, bfr, acc[0][at], 0, 0, 0, 127, 0, 127);
            acc[1][at] = __builtin_amdgcn_mfma_scale_f32_16x16x128_f8f6f4(
                p1, bfr, acc[1][at], 0, 0, 0, 127, 0, 127);
        }
        p0 = q0;
        p1 = q1;
    }
    LGKM_BAR();                                // all slab reads drained (t1 overlays)

    // ---- GEMM2 (bf16): out = h + 0.1*mask*(silu(t1) @ W2 + b2) ----
    // Full t1 (64 x 512) staged once (overlays slabs 0..8). W2 A-frags
    // streamed 2-deep from L2-resident w2p.
    float4 b1v[2];
    #pragma unroll
    for (int mt = 0; mt < 2; mt++)
        b1v[mt] = *(const float4*)&b1[wave * 32 + mt * 16 + quad * 4];

    #pragma unroll
    for (int mt = 0; mt < 2; mt++) {
        #pragma unroll
        for (int at = 0; at < 4; at++) {
            float xs[4];
            #pragma unroll
            for (int r = 0; r < 4; r++) {
                float x = acc[mt][at][r] + ((const float*)&b1v[mt])[r];
                xs[r] = x / (1.0f + __expf(-x));
            }
            uint2 pv = { pack2bf(xs[0], xs[1]), pack2bf(xs[2], xs[3]) };
            *(uint2*)&lds[(at * 16 + arow) * LDT1B + (wave * 32 + mt * 16 + quad * 4) * 2] = pv;
        }
    }
    LGKM_BAR();                                // full t1 visible; aw2 stream rides through

    float4v g2[2] = { zf, zf };                // this wave: c-tile whi, a-pair wlo

    short8 awA = *(const short8*)(w2p + ((size_t)(whi) * 64 + lane) * 8);   // ks=0
    #pragma unroll
    for (int ks2 = 0; ks2 < 8; ks2++) {
        const int k1 = 2 * ks2 + 1;
        short8 awB = *(const short8*)(w2p + ((size_t)(k1 * 8 + whi) * 64 + lane) * 8);
        #pragma unroll
        for (int j = 0; j < 2; j++) {
            short8 bt = *(const short8*)&lds[((wlo * 2 + j) * 16 + arow) * LDT1B + ((2 * ks2) * 32 + kgrp) * 2];
            g2[j] = __builtin_amdgcn_mfma_f32_16x16x32_bf16(awA, bt, g2[j], 0, 0, 0);
        }
        const int k2 = (ks2 < 7) ? 2 * ks2 + 2 : 0;   // harmless re-read on last iter
        awA = *(const short8*)(w2p + ((size_t)(k2 * 8 + whi) * 64 + lane) * 8);
        #pragma unroll
        for (int j = 0; j < 2; j++) {
            short8 bt = *(const short8*)&lds[((wlo * 2 + j) * 16 + arow) * LDT1B + ((2 * ks2 + 1) * 32 + kgrp) * 2];
            g2[j] = __builtin_amdgcn_mfma_f32_16x16x32_bf16(awB, bt, g2[j], 0, 0, 0);
        }
    }

    // D[m=c][n=a]: a = (wlo*2+j)*16+arow, c = whi*16 + quad*4 + r
    float* outh = out + (size_t)N * MA * 4 + (size_t)n * MA * F;
    const int c0 = whi * 16 + quad * 4;
    float4 b2v = *(const float4*)&b2[c0];
    #pragma unroll
    for (int j = 0; j < 2; j++) {
        int a = (wlo * 2 + j) * 16 + arow;
        float m = r_lds[a][3] * 0.1f;
        float4 hv = *(const float4*)&hg[a * F + c0];
        float4 res;
        res.x = hv.x + (g2[j][0] + b2v.x) * m;
        res.y = hv.y + (g2[j][1] + b2v.y) * m;
        res.z = hv.z + (g2[j][2] + b2v.z) * m;
        res.w = hv.w + (g2[j][3] + b2v.w) * m;
        *(float4*)&outh[(size_t)a * F + c0] = res;
    }
}

extern "C" void kernel_launch(void* const* d_in, const int* in_sizes, int n_in,
                              void* d_out, int out_size, void* d_ws, size_t ws_size,
                              hipStream_t stream) {
    const int*   z    = (const int*)d_in[0];
    const float* rr   = (const float*)d_in[1];
    const float* h    = (const float*)d_in[2];
    const float* dist = (const float*)d_in[3];
    const float* wid  = (const float*)d_in[4];
    const float* W1   = (const float*)d_in[5];
    const float* b1   = (const float*)d_in[6];
    const float* W2   = (const float*)d_in[7];
    const float* b2   = (const float*)d_in[8];
    float* out = (float*)d_out;

    int Nmol = in_sizes[0] / MA;                           // 512 molecules

    unsigned char*  w1p = (unsigned char*)d_ws;            // 544*64*32 = 1,114,112 B
    unsigned short* w2p = (unsigned short*)(w1p + (size_t)544 * 64 * 32);  // 128 KB bf16

    pack_frags<<<168, 256, 0, stream>>>(W1, W2, w1p, w2p);
    node_conv_mfma<<<Nmol, 1024, 0, stream>>>(z, rr, h, dist, wid, b1, b2, w1p, w2p, out);
}

// Round 12
// 147.091 us; speedup vs baseline: 1.0204x; 1.0204x over previous
//
#include <hip/hip_runtime.h>

#define MA 64
#define F 128
#define NF 16
#define HID 512
#define SLAB 8192   // one slab: 64 x 128 fp8 (h / u_f) OR 64 x 64 bf16 (w_f) - both 8KB
#define HT 139264   // h^T bf16 slab base (128 rows(c) x 64 cols(b) x 2B, 128B rows)
#define LDT1B 1040  // t1 row stride bytes (512 bf16 + 8 pad elems)
// 16B-granular XOR swizzle for all 128B-row slabs (slabs, h^T): row's low bits
// spread the 16-lane column-slice across 8 16B slots -> 2-way (free) banks.
// Applied on BOTH write and read sides everywhere.
#define SWZ(row, col) ((((row) * 128) + (col)) ^ (((row) & 7) << 4))

typedef float  float4v __attribute__((ext_vector_type(4)));
typedef short  short8  __attribute__((ext_vector_type(8)));
typedef int    int8v   __attribute__((ext_vector_type(8)));

// pack two fp32 -> (bf16(y)<<16)|bf16(x), round-half-up via +0x8000 then v_perm
static __device__ __forceinline__ unsigned int pack2bf(float x, float y) {
    unsigned int a = __float_as_uint(x) + 0x8000u;
    unsigned int b = __float_as_uint(y) + 0x8000u;
    return __builtin_amdgcn_perm(b, a, 0x07060302u);
}
static __device__ __forceinline__ unsigned short f2bf1(float x) {
    return (unsigned short)((__float_as_uint(x) + 0x8000u) >> 16);
}
// pack 4 fp32 -> 4 fp8 e4m3 (RNE, saturating) in one dword
static __device__ __forceinline__ unsigned int pk4fp8(float a, float b, float c, float d) {
    int p = __builtin_amdgcn_cvt_pk_fp8_f32(a, b, 0, false);
    p = __builtin_amdgcn_cvt_pk_fp8_f32(c, d, p, true);
    return (unsigned int)p;
}

// lgkm-only barrier: LDS producer/consumer sync WITHOUT draining vmcnt.
#define LGKM_BAR() do {                                        \
    asm volatile("s_waitcnt lgkmcnt(0)" ::: "memory");         \
    __builtin_amdgcn_s_barrier();                              \
    asm volatile("" ::: "memory");                             \
} while (0)

// ---- Pack W1 as fp8 MX A-frags (16x16x128) of W1^T; W2 as bf16 A-frags
// (16x16x32) of W2^T. Direct gather. (unchanged)
__global__ void pack_frags(const float* __restrict__ W1, const float* __restrict__ W2,
                           unsigned char* __restrict__ w1p, unsigned short* __restrict__ w2p) {
    int gid  = blockIdx.x * 4 + (threadIdx.x >> 6);
    int lane = threadIdx.x & 63;
    int arow = lane & 15;
    int kq   = lane >> 4;
    if (gid < 544) {                           // W1: kt (17 over K=2176, 128 each) x jt (32)
        int kt = gid >> 5, jt = gid & 31;
        const float* base = W1 + (size_t)(kt * 128 + kq * 32) * HID + jt * 16 + arow;
        unsigned int o[8];
        #pragma unroll
        for (int p = 0; p < 8; p++)
            o[p] = pk4fp8(base[(p * 4 + 0) * HID], base[(p * 4 + 1) * HID],
                          base[(p * 4 + 2) * HID], base[(p * 4 + 3) * HID]);
        unsigned char* dst = w1p + ((size_t)gid * 64 + lane) * 32;
        *(uint4*)dst        = (uint4){o[0], o[1], o[2], o[3]};
        *(uint4*)(dst + 16) = (uint4){o[4], o[5], o[6], o[7]};
    } else if (gid < 544 + 128) {              // W2: kt (16 over J=512) x mt (8 over 128)
        int g2 = gid - 544;
        int kt = g2 >> 3, mt = g2 & 7;
        const float* base = W2 + (size_t)(kt * 32 + kq * 8) * F + mt * 16 + arow;
        short8 o;
        #pragma unroll
        for (int j = 0; j < 8; j++) o[j] = (short)f2bf1(base[j * F]);
        *(short8*)(w2p + ((size_t)g2 * 64 + lane) * 8) = o;
    }
}

// ---- Main fused kernel: ONE molecule per block, 1024 threads = 16 waves ----
// FULLY PARALLEL DEPENDENCY GRAPH, 5 barriers total (was 19). r11 showed
// phase-2 (zero barriers) is fine; the cost was phase-1's 17 serial
// w->barrier->u->barrier intervals. Those are artificial: every w_f depends
// only on dpre, every u_f only on (w_f, h). Keys: (1) w_f is SYMMETRIC ->
// [a][b] store doubles as the [b][a] B-operand; (2) w_f (8KB bf16) and u_f
// (8KB fp8) are the same size and w_f is read ONLY by wave f -> wave f reads
// w_f to registers then overwrites the slab IN-PLACE with u_f (intra-wave
// WAR, no barrier); (3) h^T bf16 slab gives phase-1 A-frags via b128 LDS.
// Flow: stage(h, h^T) -> sync -> exp ALL 16 w_f -> bar -> 16 waves each
// compute whole u_f (64 bf16 MFMA, independent) -> bar -> phase-2 GEMM1
// (17 MX segs, zero barriers, W1 streamed from L2 read-once) -> bar -> t1
// -> bar -> GEMM2. All slab accesses SWZ-swizzled on both sides.
__launch_bounds__(1024, 4)
__global__ void node_conv_mfma(const int* __restrict__ z, const float* __restrict__ rr,
        const float* __restrict__ h, const float* __restrict__ dist,
        const float* __restrict__ wid, const float* __restrict__ b1,
        const float* __restrict__ b2,
        const unsigned char* __restrict__ w1p, const unsigned short* __restrict__ w2p,
        float* __restrict__ out) {
    const int n = blockIdx.x;                  // molecule index
    const int tid = threadIdx.x;
    const int lane = tid & 63;
    const int wave = tid >> 6;                 // 0..15
    const int arow = lane & 15;
    const int quad = lane >> 4;
    const int kgrp = quad * 8;
    const int whi = wave >> 1;                 // GEMM2: c-tile
    const int wlo = wave & 1;                  // GEMM2: a-pair selector

    __shared__ __attribute__((aligned(16))) unsigned char lds[155648];
    __shared__ float r_lds[MA][5];             // xyz + mask, stride-5

    const int N = gridDim.x;
    const float* hg = h + (size_t)n * MA * F;

    // ---- z / r passthrough + r/mask staging ----
    if (tid < MA) {
        int zi = z[n * MA + tid];
        out[(size_t)n * MA + tid] = (float)zi;
        r_lds[tid][0] = rr[(n * MA + tid) * 3 + 0];
        r_lds[tid][1] = rr[(n * MA + tid) * 3 + 1];
        r_lds[tid][2] = rr[(n * MA + tid) * 3 + 2];
        r_lds[tid][3] = (zi > -1) ? 1.0f : 0.0f;
    }
    if (tid < MA * 3)
        out[(size_t)N * MA + (size_t)n * MA * 3 + tid] = rr[(size_t)n * MA * 3 + tid];

    // ---- stage h -> slab 0 (row-major [b][c] fp8, swizzled) ----
    for (int i = tid; i < MA * F / 4; i += 1024) {
        float4 v = ((const float4*)hg)[i];
        int a = i >> 5, c4 = (i & 31) * 4;
        *(unsigned int*)&lds[SWZ(a, c4)] = pk4fp8(v.x, v.y, v.z, v.w);
    }
    // ---- stage h^T -> HT (row-major [c][b] bf16, swizzled) ----
    for (int i = tid; i < MA * F; i += 1024) {
        int b = i >> 7, c = i & 127;
        *(unsigned short*)&lds[HT + SWZ(c, b * 2)] = f2bf1(hg[i]);
    }
    __syncthreads();                           // barrier 1: r_lds + h + h^T visible

    // ---- per-thread pairwise distances (4 pairs/thread), mask folded in ----
    const int wa = tid >> 4;                   // 0..63
    const int wb0 = (tid & 15) * 4;            // 0,4,..,60
    float dpre[4];
    {
        float ax = r_lds[wa][0], ay = r_lds[wa][1], az = r_lds[wa][2];
        float am = r_lds[wa][3];
        #pragma unroll
        for (int j = 0; j < 4; j++) {
            float dx = ax - r_lds[wb0 + j][0];
            float dy = ay - r_lds[wb0 + j][1];
            float dz = az - r_lds[wb0 + j][2];
            float d = sqrtf(dx * dx + dy * dy + dz * dz + 1e-12f);
            float mm = am * r_lds[wb0 + j][3];
            dpre[j] = d + (1.0f - mm) * 1e4f;  // exp underflows to 0 when masked
        }
    }

    // ---- exp ALL 16 filters -> slabs 1..16 ([a][b] bf16 64x64, swizzled).
    // No barriers between filters: fully pipelineable exp+pack+ds_write burst.
    #pragma unroll
    for (int f = 0; f < NF; f++) {
        float mu = dist[f];
        float isg = 1.0f / wid[f];
        float e[4];
        #pragma unroll
        for (int j = 0; j < 4; j++) {
            float t = dpre[j] - mu;
            e[j] = 5.0f * __expf(-t * t * isg);
        }
        uint2 wp = { pack2bf(e[0], e[1]), pack2bf(e[2], e[3]) };
        *(uint2*)&lds[(f + 1) * SLAB + SWZ(wa, wb0 * 2)] = wp;
    }
    LGKM_BAR();                                // barrier 2: all w slabs visible

    const float4v zf = {0.f, 0.f, 0.f, 0.f};

    // ---- per-wave u_f = w_f @ h (f = wave), IN-PLACE over w_f's slab ----
    // wB: B[k=b][n=a] frags of symmetric w_f ([a][b] row serves as [b][a]):
    // lane n = arow, k = ks*32+kgrp+j. Read ALL 8 frags to regs first, then
    // overwrite the slab with u_f (intra-wave WAR; ds ops ordered in-wave).
    {
        const int ws = (wave + 1) * SLAB;
        short8 wB[4][2];
        #pragma unroll
        for (int at = 0; at < 4; at++)
            #pragma unroll
            for (int ks = 0; ks < 2; ks++)
                wB[at][ks] = *(const short8*)&lds[ws + SWZ(at * 16 + arow, (ks * 32 + kgrp) * 2)];

        #pragma unroll
        for (int cp = 0; cp < 4; cp++) {       // c in chunks of 32 (2 c-tiles)
            short8 hA[2][2];                   // A[m=c][k=b] from h^T slab
            #pragma unroll
            for (int cc = 0; cc < 2; cc++)
                #pragma unroll
                for (int ks = 0; ks < 2; ks++)
                    hA[cc][ks] = *(const short8*)&lds[HT + SWZ((cp * 2 + cc) * 16 + arow, (ks * 32 + kgrp) * 2)];
            float4v ud[2][4];                  // D[m=c][n=a]: 8 tiles = 32 AGPR
            #pragma unroll
            for (int cc = 0; cc < 2; cc++)
                #pragma unroll
                for (int at = 0; at < 4; at++) ud[cc][at] = zf;
            #pragma unroll
            for (int cc = 0; cc < 2; cc++)
                #pragma unroll
                for (int at = 0; at < 4; at++)
                    #pragma unroll
                    for (int ks = 0; ks < 2; ks++)
                        ud[cc][at] = __builtin_amdgcn_mfma_f32_16x16x32_bf16(
                            hA[cc][ks], wB[at][ks], ud[cc][at], 0, 0, 0);
            // store u_f[a][c] fp8: lane col a = at*16+arow, rows c = quad*4+r
            #pragma unroll
            for (int cc = 0; cc < 2; cc++)
                #pragma unroll
                for (int at = 0; at < 4; at++) {
                    unsigned int up = pk4fp8(ud[cc][at][0], ud[cc][at][1],
                                             ud[cc][at][2], ud[cc][at][3]);
                    *(unsigned int*)&lds[ws + SWZ(at * 16 + arow, (cp * 2 + cc) * 16 + quad * 4)] = up;
                }
        }
    }

    // seg-0 W1 A-frag pair: issue now, rides the barrier on vmcnt
    int8v p0, p1, q0, q1;
    {
        const unsigned char* pp = w1p + ((size_t)((wave * 2) * 64 + lane)) * 32;
        p0 = *(const int8v*)pp;
        p1 = *(const int8v*)(pp + 2048);
    }
    LGKM_BAR();                                // barrier 3: all u slabs visible

    // ---- PHASE 2: GEMM1, 17 K-segments, ZERO barriers (r11-verified) ----
    float4v acc[2][4];                         // [mt = j-tile][at = a-tile] = 32 AGPRs
    #pragma unroll
    for (int i = 0; i < 2; i++)
        #pragma unroll
        for (int jv = 0; jv < 4; jv++) acc[i][jv] = zf;

    for (int f = 0; f <= NF; f++) {
        if (f < NF) {                          // prefetch next segment's A-frag pair
            const unsigned char* pq = w1p + ((size_t)(((f + 1) * 32 + wave * 2) * 64 + lane)) * 32;
            q0 = *(const int8v*)pq;
            q1 = *(const int8v*)(pq + 2048);
        }
        const int sb = f * SLAB;
        #pragma unroll
        for (int at = 0; at < 4; at++) {
            const int rowb = at * 16 + arow;
            uint4 lo = *(const uint4*)&lds[sb + SWZ(rowb, quad * 32)];
            uint4 hi = *(const uint4*)&lds[sb + SWZ(rowb, quad * 32 + 16)];
            int8v bfr;
            bfr[0] = (int)lo.x; bfr[1] = (int)lo.y; bfr[2] = (int)lo.z; bfr[3] = (int)lo.w;
            bfr[4] = (int)hi.x; bfr[5] = (int)hi.y; bfr[6] = (int)hi.z; bfr[7] = (int)hi.w;
            acc[0][at] = __builtin_amdgcn_mfma_scale_f32_16x16x128_f8f6f4(
                p0, bfr, acc[0][at], 0, 0, 0, 127, 0, 127);
            acc[1][at] = __builtin_amdgcn_mfma_scale_f32_16x16x128_f8f6f4(
                p1, bfr, acc[1][at], 0, 0, 0, 127, 0, 127);
        }
        p0 = q0;
        p1 = q1;
    }
    LGKM_BAR();                                // barrier 4: slab reads drained (t1 overlays)

    // ---- GEMM2 (bf16): out = h + 0.1*mask*(silu(t1) @ W2 + b2) ----
    float4 b1v[2];
    #pragma unroll
    for (int mt = 0; mt < 2; mt++)
        b1v[mt] = *(const float4*)&b1[wave * 32 + mt * 16 + quad * 4];

    #pragma unroll
    for (int mt = 0; mt < 2; mt++) {
        #pragma unroll
        for (int at = 0; at < 4; at++) {
            float xs[4];
            #pragma unroll
            for (int r = 0; r < 4; r++) {
                float x = acc[mt][at][r] + ((const float*)&b1v[mt])[r];
                xs[r] = x / (1.0f + __expf(-x));
            }
            uint2 pv = { pack2bf(xs[0], xs[1]), pack2bf(xs[2], xs[3]) };
            *(uint2*)&lds[(at * 16 + arow) * LDT1B + (wave * 32 + mt * 16 + quad * 4) * 2] = pv;
        }
    }
    LGKM_BAR();                                // barrier 5: full t1 visible; aw2 rides

    float4v g2[2] = { zf, zf };                // this wave: c-tile whi, a-pair wlo

    short8 awA = *(const short8*)(w2p + ((size_t)(whi) * 64 + lane) * 8);   // ks=0
    #pragma unroll
    for (int ks2 = 0; ks2 < 8; ks2++) {
        const int k1 = 2 * ks2 + 1;
        short8 awB = *(const short8*)(w2p + ((size_t)(k1 * 8 + whi) * 64 + lane) * 8);
        #pragma unroll
        for (int j = 0; j < 2; j++) {
            short8 bt = *(const short8*)&lds[((wlo * 2 + j) * 16 + arow) * LDT1B + ((2 * ks2) * 32 + kgrp) * 2];
            g2[j] = __builtin_amdgcn_mfma_f32_16x16x32_bf16(awA, bt, g2[j], 0, 0, 0);
        }
        const int k2 = (ks2 < 7) ? 2 * ks2 + 2 : 0;   // harmless re-read on last iter
        awA = *(const short8*)(w2p + ((size_t)(k2 * 8 + whi) * 64 + lane) * 8);
        #pragma unroll
        for (int j = 0; j < 2; j++) {
            short8 bt = *(const short8*)&lds[((wlo * 2 + j) * 16 + arow) * LDT1B + ((2 * ks2 + 1) * 32 + kgrp) * 2];
            g2[j] = __builtin_amdgcn_mfma_f32_16x16x32_bf16(awB, bt, g2[j], 0, 0, 0);
        }
    }

    // D[m=c][n=a]: a = (wlo*2+j)*16+arow, c = whi*16 + quad*4 + r
    float* outh = out + (size_t)N * MA * 4 + (size_t)n * MA * F;
    const int c0 = whi * 16 + quad * 4;
    float4 b2v = *(const float4*)&b2[c0];
    #pragma unroll
    for (int j = 0; j < 2; j++) {
        int a = (wlo * 2 + j) * 16 + arow;
        float m = r_lds[a][3] * 0.1f;
        float4 hv = *(const float4*)&hg[a * F + c0];
        float4 res;
        res.x = hv.x + (g2[j][0] + b2v.x) * m;
        res.y = hv.y + (g2[j][1] + b2v.y) * m;
        res.z = hv.z + (g2[j][2] + b2v.z) * m;
        res.w = hv.w + (g2[j][3] + b2v.w) * m;
        *(float4*)&outh[(size_t)a * F + c0] = res;
    }
}

extern "C" void kernel_launch(void* const* d_in, const int* in_sizes, int n_in,
                              void* d_out, int out_size, void* d_ws, size_t ws_size,
                              hipStream_t stream) {
    const int*   z    = (const int*)d_in[0];
    const float* rr   = (const float*)d_in[1];
    const float* h    = (const float*)d_in[2];
    const float* dist = (const float*)d_in[3];
    const float* wid  = (const float*)d_in[4];
    const float* W1   = (const float*)d_in[5];
    const float* b1   = (const float*)d_in[6];
    const float* W2   = (const float*)d_in[7];
    const float* b2   = (const float*)d_in[8];
    float* out = (float*)d_out;

    int Nmol = in_sizes[0] / MA;                           // 512 molecules

    unsigned char*  w1p = (unsigned char*)d_ws;            // 544*64*32 = 1,114,112 B
    unsigned short* w2p = (unsigned short*)(w1p + (size_t)544 * 64 * 32);  // 128 KB bf16

    pack_frags<<<168, 256, 0, stream>>>(W1, W2, w1p, w2p);
    node_conv_mfma<<<Nmol, 1024, 0, stream>>>(z, rr, h, dist, wid, b1, b2, w1p, w2p, out);
}